// Round 32
// baseline (261.444 us; speedup 1.0000x reference)
//
#include <hip/hip_runtime.h>
#include <cstdint>
#include <cstddef>

#define NPTS 4096
#define KNB 32
#define EPSC 1e-5f
#define NC 6            // grid cells per axis (1/6 = 0.1667 >= 0.15 ball radius)
#define NCELL (NC*NC*NC)

typedef short short8v __attribute__((ext_vector_type(8)));
typedef float f32x4 __attribute__((ext_vector_type(4)));
typedef unsigned short u16;

__device__ __forceinline__ u16 f2bf(float x) {
    unsigned u = __float_as_uint(x);
    u = (u + 0x7FFFu + ((u >> 16) & 1u)) >> 16;
    return (u16)u;
}
__device__ __forceinline__ float bf2f(u16 h) {
    return __uint_as_float((unsigned)h << 16);
}

// ---------------------------------------------------------------------------
// splits: f32 -> (bf16 hi, bf16 lo)
// ---------------------------------------------------------------------------
__global__ __launch_bounds__(256) void split_kernel(
    const float* __restrict__ src, u16* __restrict__ hi, u16* __restrict__ lo, int n)
{
    int i = blockIdx.x * 256 + threadIdx.x;
    if (i < n) {
        float v = src[i];
        u16 h = f2bf(v);
        hi[i] = h;
        lo[i] = f2bf(v - bf2f(h));
    }
}
__global__ __launch_bounds__(256) void split_w1_kernel(
    const float* __restrict__ W1, u16* __restrict__ hi, u16* __restrict__ lo)
{
    int i = blockIdx.x * 256 + threadIdx.x;      // 16384
    int n = i >> 7, k = i & 127;
    float v = W1[n * 131 + 3 + k];
    u16 h = f2bf(v);
    hi[i] = h;
    lo[i] = f2bf(v - bf2f(h));
}

// ---------------------------------------------------------------------------
// Kernel G: per-batch grid build (counting sort) + pos passthrough.
// ---------------------------------------------------------------------------
__global__ __launch_bounds__(1024) void grid_build_kernel(
    const float* __restrict__ pos, int* __restrict__ gsorted,
    int* __restrict__ gstarts, float* __restrict__ pos_out)
{
    __shared__ int cnt[NCELL];
    __shared__ int st[NCELL + 1];
    const int b = blockIdx.x;
    const int tid = threadIdx.x;
    const float* pb = pos + (size_t)b * NPTS * 3;

    for (int c = tid; c < NCELL; c += 1024) cnt[c] = 0;
    __syncthreads();
    for (int j = tid; j < NPTS; j += 1024) {
        const float x = pb[j*3+0], y = pb[j*3+1], z = pb[j*3+2];
        int ix = (int)(x * 6.0f); ix = ix > 5 ? 5 : ix;
        int iy = (int)(y * 6.0f); iy = iy > 5 ? 5 : iy;
        int iz = (int)(z * 6.0f); iz = iz > 5 ? 5 : iz;
        atomicAdd(&cnt[(iz * NC + iy) * NC + ix], 1);
    }
    {   // pos passthrough
        const float4* src = (const float4*)pb;
        float4* dst = (float4*)(pos_out + (size_t)b * NPTS * 3);
        for (int i = tid; i < NPTS * 3 / 4; i += 1024) dst[i] = src[i];
    }
    __syncthreads();
    if (tid == 0) {
        int a = 0;
        for (int c = 0; c < NCELL; ++c) { st[c] = a; a += cnt[c]; }
        st[NCELL] = a;
    }
    __syncthreads();
    for (int c = tid; c < NCELL + 1; c += 1024) gstarts[b * (NCELL + 1) + c] = st[c];
    for (int c = tid; c < NCELL; c += 1024) cnt[c] = 0;
    __syncthreads();
    for (int j = tid; j < NPTS; j += 1024) {
        const float x = pb[j*3+0], y = pb[j*3+1], z = pb[j*3+2];
        int ix = (int)(x * 6.0f); ix = ix > 5 ? 5 : ix;
        int iy = (int)(y * 6.0f); iy = iy > 5 ? 5 : iy;
        int iz = (int)(z * 6.0f); iz = iz > 5 ? 5 : iz;
        const int cid = (iz * NC + iy) * NC + ix;
        const int slot = st[cid] + atomicAdd(&cnt[cid], 1);
        gsorted[b * NPTS + slot] = j;
    }
}

// ---------------------------------------------------------------------------
// Kernel A: grid-pruned ball query with BITMAP selection (r28).
// ---------------------------------------------------------------------------
__device__ __forceinline__ int wave_min64(int m) {
#pragma unroll
    for (int s = 1; s < 64; s <<= 1) {
        const int o = __shfl_xor(m, s);
        m = m < o ? m : o;
    }
    return m;
}

template<bool BAND>
__device__ __forceinline__ int gather_bits(
    const float4* __restrict__ spos, const int* __restrict__ sst,
    unsigned* __restrict__ bm,
    float px, float py, float pz, int lane, float thr, float tlo)
{
    bm[lane] = 0u; bm[64 + lane] = 0u;               // zero wave-private bitmap
    int cxi = (int)(px * 6.0f); cxi = cxi > 5 ? 5 : cxi;
    int cyi = (int)(py * 6.0f); cyi = cyi > 5 ? 5 : cyi;
    int czi = (int)(pz * 6.0f); czi = czi > 5 ? 5 : czi;
    const int x0 = cxi > 0 ? cxi - 1 : 0, x1 = cxi < 5 ? cxi + 1 : 5;
    const int y0 = cyi > 0 ? cyi - 1 : 0, y1 = cyi < 5 ? cyi + 1 : 5;
    const int z0 = czi > 0 ? czi - 1 : 0, z1 = czi < 5 ? czi + 1 : 5;
    int anyband = 0;
    for (int zz = z0; zz <= z1; ++zz)
    for (int yy = y0; yy <= y1; ++yy) {
        const int cb = (zz * NC + yy) * NC;
        const int s = sst[cb + x0];
        const int e = sst[cb + x1 + 1];
        for (int off = s; off < e; off += 64) {
            const int ii = off + lane;
            bool hit = false, band = false;
            int j = 0;
            if (ii < e) {
                const float4 c = spos[ii];
                const float dx = px - c.x;
                const float dy = py - c.y;
                const float dz = pz - c.z;
                const float d2 = fmaf(dx, dx, fmaf(dy, dy, dz * dz));
                hit = d2 < thr;
                band = BAND && hit && !(d2 < tlo);
                j = __float_as_int(c.w);
            }
            if (BAND)
                anyband |= (__ballot(band) != 0ull) ? 1 : 0;
            if (hit)
                atomicOr(&bm[j >> 5], 1u << (j & 31));
        }
    }
    return anyband;
}

__device__ __forceinline__ void select32_bitmap(
    const unsigned* __restrict__ bm, int lane, int* __restrict__ outp)
{
    unsigned w0 = bm[2 * lane], w1 = bm[2 * lane + 1];
    const int c = __popc(w0) + __popc(w1);
    int pre = c;                                     // inclusive prefix sum
#pragma unroll
    for (int s = 1; s < 64; s <<= 1) {
        const int o = __shfl_up(pre, s);
        if (lane >= s) pre += o;
    }
    const int total = __shfl(pre, 63);
    int r = pre - c;                                 // exclusive prefix
    int myfirst = 0x7FFFFFFF;
    if (w0) myfirst = lane * 64 + (__ffs(w0) - 1);
    else if (w1) myfirst = lane * 64 + 32 + (__ffs(w1) - 1);
    const int firstj = wave_min64(myfirst);          // smallest hit index
    const int base = lane * 64;
    while (w0 && r < KNB) {
        const int bpos = __ffs(w0) - 1;
        outp[r++] = base + bpos;
        w0 &= w0 - 1;
    }
    while (w1 && r < KNB) {
        const int bpos = __ffs(w1) - 1;
        outp[r++] = base + 32 + bpos;
        w1 &= w1 - 1;
    }
    const int stored = total < KNB ? total : KNB;
    if (lane >= stored && lane < KNB) outp[lane] = firstj;   // pad w/ first hit
}

__global__ __launch_bounds__(1024) void ball_query_kernel(
    const float* __restrict__ pos, const int* __restrict__ gsorted,
    const int* __restrict__ gstarts,
    int* __restrict__ idx_inc, int* __restrict__ idx_exc,
    int* __restrict__ flags)
{
    __shared__ float4 spos[NPTS];                    // 64 KB, sorted order
    __shared__ int sst[NCELL + 2];
    __shared__ unsigned bmap[16][128];               // 8 KB (wave-private)
    const int tid  = threadIdx.x;
    const int lane = tid & 63;
    const int wv   = tid >> 6;
    const int pbase = blockIdx.x * 64;               // 64 points per block
    const int b = pbase >> 12;
    const float* pb = pos + (size_t)b * NPTS * 3;

    const float T_HI = (float)(0.0225 + 3e-7);
    const float T_LO = (float)(0.0225 - 3e-7);

    for (int i = tid; i < NPTS; i += 1024) {
        const int j = gsorted[b * NPTS + i];
        spos[i] = make_float4(pb[j*3+0], pb[j*3+1], pb[j*3+2],
                              __int_as_float(j));
    }
    if (tid < NCELL + 1) sst[tid] = gstarts[b * (NCELL + 1) + tid];
    __syncthreads();

    unsigned* bm = bmap[wv];
    for (int pi = 0; pi < 4; ++pi) {
        const int p = pbase + wv * 4 + pi;
        const int ml = p & (NPTS - 1);
        const float px = pb[ml*3+0], py = pb[ml*3+1], pz = pb[ml*3+2];
        const int flg = gather_bits<true>(spos, sst, bm, px, py, pz,
                                          lane, T_HI, T_LO);
        select32_bitmap(bm, lane, idx_inc + (size_t)p * KNB);
        if (flg) {                                   // rare, wave-uniform
            gather_bits<false>(spos, sst, bm, px, py, pz, lane, T_LO, T_LO);
            select32_bitmap(bm, lane, idx_exc + (size_t)p * KNB);
        }
        if (lane == 0) flags[p] = flg;
    }
}

// ---------------------------------------------------------------------------
// MFMA split-bf16 GEMM, BM x 128 tile, register double-buffer prefetch (r24).
// CVTA: A is f32, converted during staging.
// ---------------------------------------------------------------------------
template<int BM, int KTOT, bool CVTA>
__device__ __forceinline__ void mfma_load_chunk(
    const u16* __restrict__ Ahg, const u16* __restrict__ Alg,
    const float* __restrict__ Af32,
    const u16* __restrict__ Whg, const u16* __restrict__ Wlg,
    int rowbase, int colbase, int arow, int ak, int brow, int bk, int kc,
    short8v* pAh, short8v* pAl, short8v* pBh, short8v* pBl)
{
    constexpr int APT = BM / 8;
    constexpr int NSEG = APT / 8;
    const size_t ga = (size_t)(rowbase + arow) * KTOT + kc * 32 + ak;
    if constexpr (CVTA) {
        float vals[APT];
#pragma unroll
        for (int s4 = 0; s4 < APT / 4; ++s4)
            *(float4*)&vals[s4 * 4] = *(const float4*)&Af32[ga + s4 * 4];
        u16 hi16[APT], lo16[APT];
#pragma unroll
        for (int i = 0; i < APT; ++i) {
            const u16 h = f2bf(vals[i]);
            hi16[i] = h;
            lo16[i] = f2bf(vals[i] - bf2f(h));
        }
#pragma unroll
        for (int s = 0; s < NSEG; ++s) {
            pAh[s] = *(const short8v*)&hi16[s * 8];
            pAl[s] = *(const short8v*)&lo16[s * 8];
        }
    } else {
#pragma unroll
        for (int s = 0; s < NSEG; ++s) {
            pAh[s] = *(const short8v*)&Ahg[ga + s * 8];
            pAl[s] = *(const short8v*)&Alg[ga + s * 8];
        }
    }
    const size_t gw = (size_t)(colbase + brow) * KTOT + kc * 32 + bk;
    pBh[0] = *(const short8v*)&Whg[gw];
    pBh[1] = *(const short8v*)&Whg[gw + 8];
    pBl[0] = *(const short8v*)&Wlg[gw];
    pBl[1] = *(const short8v*)&Wlg[gw + 8];
}

template<int BM, int KTOT, int EPI, bool CVTA>
__global__ __launch_bounds__(256) void mfma_gemm_kernel(
    const u16* __restrict__ Ahg, const u16* __restrict__ Alg,
    const float* __restrict__ Af32,
    const u16* __restrict__ Whg, const u16* __restrict__ Wlg,
    const float* __restrict__ gg, const float* __restrict__ bb,
    const float* __restrict__ mm, const float* __restrict__ vv,
    const float* __restrict__ X,
    u16* __restrict__ Oh, u16* __restrict__ Ol,
    float* __restrict__ Yf, int nstride)
{
    constexpr int MI   = BM / 32;    // 16-row frags per wave
    constexpr int APT  = BM / 8;     // A u16 per thread per array
    constexpr int NSEG = APT / 8;
    constexpr int NK   = KTOT / 32;
    __shared__ u16 Ah[BM][40];
    __shared__ u16 Al[BM][40];
    __shared__ u16 Bh[128][40];
    __shared__ u16 Bl[128][40];
    const int tid  = threadIdx.x;
    const int lane = tid & 63;
    const int wv   = tid >> 6;
    const int rowbase = blockIdx.x * BM;
    const int colbase = blockIdx.y * 128;
    const int R0 = (wv >> 1) * (BM / 2);
    const int C0 = (wv & 1) * 64;
    const int aoff = tid * APT;
    const int arow = aoff >> 5;
    const int ak   = aoff & 31;
    const int brow = tid >> 1;
    const int bk   = (tid & 1) * 16;
    const int fr = lane & 15;
    const int fq = lane >> 4;

    f32x4 acc[MI][4];
#pragma unroll
    for (int i = 0; i < MI; ++i)
#pragma unroll
        for (int j = 0; j < 4; ++j)
            acc[i][j] = (f32x4){0.f, 0.f, 0.f, 0.f};

    short8v pAh[NSEG], pAl[NSEG], pBh[2], pBl[2];
    mfma_load_chunk<BM, KTOT, CVTA>(Ahg, Alg, Af32, Whg, Wlg,
        rowbase, colbase, arow, ak, brow, bk, 0, pAh, pAl, pBh, pBl);

    for (int kc = 0; kc < NK; ++kc) {
        __syncthreads();                 // prior compute done reading LDS
#pragma unroll
        for (int s = 0; s < NSEG; ++s) {
            *(short8v*)&Ah[arow][ak + s * 8] = pAh[s];
            *(short8v*)&Al[arow][ak + s * 8] = pAl[s];
        }
        *(short8v*)&Bh[brow][bk]     = pBh[0];
        *(short8v*)&Bh[brow][bk + 8] = pBh[1];
        *(short8v*)&Bl[brow][bk]     = pBl[0];
        *(short8v*)&Bl[brow][bk + 8] = pBl[1];
        if (kc + 1 < NK)                 // prefetch next chunk (latency hidden)
            mfma_load_chunk<BM, KTOT, CVTA>(Ahg, Alg, Af32, Whg, Wlg,
                rowbase, colbase, arow, ak, brow, bk, kc + 1, pAh, pAl, pBh, pBl);
        __syncthreads();

        short8v ahf[MI], alf[MI];
#pragma unroll
        for (int fi = 0; fi < MI; ++fi) {
            ahf[fi] = *(const short8v*)&Ah[R0 + fi * 16 + fr][fq * 8];
            alf[fi] = *(const short8v*)&Al[R0 + fi * 16 + fr][fq * 8];
        }
#pragma unroll
        for (int fj = 0; fj < 4; ++fj) {
            const short8v bh = *(const short8v*)&Bh[C0 + fj * 16 + fr][fq * 8];
            const short8v bl = *(const short8v*)&Bl[C0 + fj * 16 + fr][fq * 8];
#pragma unroll
            for (int fi = 0; fi < MI; ++fi) {
                acc[fi][fj] = __builtin_amdgcn_mfma_f32_16x16x32_bf16(ahf[fi], bh, acc[fi][fj], 0, 0, 0);
                acc[fi][fj] = __builtin_amdgcn_mfma_f32_16x16x32_bf16(ahf[fi], bl, acc[fi][fj], 0, 0, 0);
                acc[fi][fj] = __builtin_amdgcn_mfma_f32_16x16x32_bf16(alf[fi], bh, acc[fi][fj], 0, 0, 0);
            }
        }
    }

    // epilogue: D mapping row=(lane>>4)*4+reg, col=lane&15  [m89 verified]
#pragma unroll
    for (int fj = 0; fj < 4; ++fj) {
        const int col = colbase + C0 + fj * 16 + fr;
        const float sc = gg[col] / sqrtf(vv[col] + EPSC);
        const float tt = (EPI == 0) ? 0.f : (bb[col] - mm[col] * sc);
#pragma unroll
        for (int fi = 0; fi < MI; ++fi) {
#pragma unroll
            for (int r = 0; r < 4; ++r) {
                const int row = rowbase + R0 + fi * 16 + fq * 4 + r;
                float v = acc[fi][fj][r] * sc + tt;
                if (EPI == 2) v += X[(size_t)row * 128 + col];
                if (EPI >= 1) v = fmaxf(v, 0.f);
                if (EPI == 1) {
                    const u16 h = f2bf(v);
                    Oh[(size_t)row * nstride + col] = h;
                    Ol[(size_t)row * nstride + col] = f2bf(v - bf2f(h));
                } else {
                    Yf[(size_t)row * nstride + col] = v;
                }
            }
        }
    }
}

// ---------------------------------------------------------------------------
// Kernel C: gather + rel contribution + max-pool, 4 pts/wave, grid-sorted
// order (r30). XCD-affine swizzle: 256 blocks/batch on one XCD.
// ---------------------------------------------------------------------------
__global__ __launch_bounds__(256) void group_max_kernel(
    const float* __restrict__ pos, const int* __restrict__ gsorted,
    const int* __restrict__ idx_inc, const int* __restrict__ idx_exc,
    const int* __restrict__ flags, const float* __restrict__ xws,
    const float* __restrict__ W1, const float* __restrict__ g1,
    const float* __restrict__ b1, const float* __restrict__ m1,
    const float* __restrict__ v1,
    u16* __restrict__ fh, u16* __restrict__ fl, float* __restrict__ f_exc)
{
    __shared__ float4 relbuf [4][4][KNB];            // inc tables: 8 KB
    __shared__ float4 relbuf2[4][4][KNB];            // exc tables: 8 KB
    const int tid  = threadIdx.x;
    const int lane = tid & 63;
    const int wv   = tid >> 6;
    const int bid  = blockIdx.x;                     // 0..2047
    const int grp  = (bid & 7) * 256 + (bid >> 3);   // XCD-affine, bijective
    const int b = grp >> 8;                          // batch (256 blocks/batch)
    const int spos0 = (grp & 255) * 16 + wv * 4;     // sorted position of pt 0
    const float* pb = pos + (size_t)b * NPTS * 3;
    const char* xws_b = (const char*)(xws + (size_t)b * NPTS * 128);
    const int o0 = lane * 2;
    const int lane8 = lane * 8;

    const float w00 = W1[(size_t)o0*131+0], w01 = W1[(size_t)o0*131+1], w02 = W1[(size_t)o0*131+2];
    const float w10 = W1[(size_t)(o0+1)*131+0], w11 = W1[(size_t)(o0+1)*131+1], w12 = W1[(size_t)(o0+1)*131+2];
    const float s0 = g1[o0]   / sqrtf(v1[o0]   + EPSC);
    const float s1 = g1[o0+1] / sqrtf(v1[o0+1] + EPSC);
    const float t0 = b1[o0]   - m1[o0]   * s0;
    const float t1 = b1[o0+1] - m1[o0+1] * s1;
    const float q00 = w00*s0, q01 = w01*s0, q02 = w02*s0;
    const float q10 = w10*s1, q11 = w11*s1, q12 = w12*s1;

    int pact[4], flg[4];
#pragma unroll
    for (int t = 0; t < 4; ++t) {
        const int ml = gsorted[b * NPTS + spos0 + t];     // wave-uniform
        pact[t] = b * NPTS + ml;                          // actual point id
        flg[t] = flags[pact[t]];
    }

    // preload 4 inc (and rare exc) tables: 128 entries over 64 lanes, 2 passes
#pragma unroll
    for (int rep = 0; rep < 2; ++rep) {
        const int g = rep * 64 + lane;
        const int t = g >> 5, slot = g & 31;
        const int pq = pact[t];
        const int ml = pq & (NPTS - 1);
        const float cx = pb[ml*3+0], cy = pb[ml*3+1], cz = pb[ml*3+2];
        const int j = idx_inc[(size_t)pq * KNB + slot];
        const float* pj = &pb[j*3];
        relbuf[wv][t][slot] = make_float4(
            (pj[0]-cx)/0.15f, (pj[1]-cy)/0.15f, (pj[2]-cz)/0.15f,
            __int_as_float(j << 9));
        if (flg[t]) {
            const int je = idx_exc[(size_t)pq * KNB + slot];
            const float* pe = &pb[je*3];
            relbuf2[wv][t][slot] = make_float4(
                (pe[0]-cx)/0.15f, (pe[1]-cy)/0.15f, (pe[2]-cz)/0.15f,
                __int_as_float(je << 9));
        }
    }
    __syncthreads();

    {   // interleaved quad-point max-pool (4 loads in flight per k)
        float acc0[4], acc1[4];
#pragma unroll
        for (int t = 0; t < 4; ++t) { acc0[t] = 0.f; acc1[t] = 0.f; }
#pragma unroll 4
        for (int k = 0; k < KNB; ++k) {
            float4 rv[4];
#pragma unroll
            for (int t = 0; t < 4; ++t) rv[t] = relbuf[wv][t][k];
            float2 xw[4];
#pragma unroll
            for (int t = 0; t < 4; ++t)
                xw[t] = *(const float2*)(xws_b + __float_as_int(rv[t].w) + lane8);
#pragma unroll
            for (int t = 0; t < 4; ++t) {
                acc0[t] = fmaxf(acc0[t], fmaf(rv[t].x, q00, fmaf(rv[t].y, q01, fmaf(rv[t].z, q02, t0 + xw[t].x))));
                acc1[t] = fmaxf(acc1[t], fmaf(rv[t].x, q10, fmaf(rv[t].y, q11, fmaf(rv[t].z, q12, t1 + xw[t].y))));
            }
        }
#pragma unroll
        for (int t = 0; t < 4; ++t) {
            const u16 h0 = f2bf(acc0[t]); const u16 l0 = f2bf(acc0[t] - bf2f(h0));
            const u16 h1 = f2bf(acc1[t]); const u16 l1 = f2bf(acc1[t] - bf2f(h1));
            *(unsigned*)&fh[(size_t)pact[t] * 128 + o0] = (unsigned)h0 | ((unsigned)h1 << 16);
            *(unsigned*)&fl[(size_t)pact[t] * 128 + o0] = (unsigned)l0 | ((unsigned)l1 << 16);
        }
    }
#pragma unroll
    for (int t = 0; t < 4; ++t) {
        if (flg[t]) {                                // rare, wave-uniform
            const float4* rt = relbuf2[wv][t];
            float e0 = 0.f, e1 = 0.f;
#pragma unroll 8
            for (int k = 0; k < KNB; ++k) {
                const float4 rv = rt[k];
                const float2 xw = *(const float2*)(xws_b + __float_as_int(rv.w) + lane8);
                e0 = fmaxf(e0, fmaf(rv.x, q00, fmaf(rv.y, q01, fmaf(rv.z, q02, t0 + xw.x))));
                e1 = fmaxf(e1, fmaf(rv.x, q10, fmaf(rv.y, q11, fmaf(rv.z, q12, t1 + xw.y))));
            }
            float2 ev; ev.x = e0; ev.y = e1;
            *(float2*)&f_exc[(size_t)pact[t] * 128 + o0] = ev;
        }
    }
}

// ---------------------------------------------------------------------------
// Kernel E: fixup with COALESCED wave-per-row reductions. Each block owns 4
// candidate points; per flagged point: f_exc -> LDS; W2 pass = wave w handles
// rows [w*128, w*128+128), lanes read wr[lane]/wr[64+lane] (coalesced 256B),
// butterfly-reduce, lane0 writes hsh; W3 pass analogous (8 segments). No
// strided 64-line gathers. Flag pattern block-uniform -> barriers legal.
// ---------------------------------------------------------------------------
__global__ __launch_bounds__(256) void fixup_kernel(
    const int* __restrict__ flags, const float* __restrict__ f_exc,
    const float* __restrict__ x,
    const float* __restrict__ W2, const float* __restrict__ g2,
    const float* __restrict__ b2, const float* __restrict__ m2,
    const float* __restrict__ v2,
    const float* __restrict__ W3, const float* __restrict__ g3,
    const float* __restrict__ b3, const float* __restrict__ m3,
    const float* __restrict__ v3,
    float* __restrict__ y_out)
{
    const int tid  = threadIdx.x;
    const int lane = tid & 63;
    const int wv   = tid >> 6;
    const int bid  = blockIdx.x;
    const int grp  = (bid & 7) * 1024 + (bid >> 3);
    const int p0 = grp * 4;

    int flg[4];
#pragma unroll
    for (int t = 0; t < 4; ++t) flg[t] = flags[p0 + t];
    if (!(flg[0] | flg[1] | flg[2] | flg[3])) return;

    __shared__ float fsh[128];
    __shared__ float hsh[512];

    for (int t = 0; t < 4; ++t) {
        if (!flg[t]) continue;                       // block-uniform
        const int p = p0 + t;
        __syncthreads();                             // protect LDS reuse
        if (tid < 64) {
            const float2 v = *(const float2*)&f_exc[(size_t)p * 128 + 2 * tid];
            fsh[2 * tid] = v.x; fsh[2 * tid + 1] = v.y;
        }
        __syncthreads();
        // W2 pass: wave w -> rows [w*128, (w+1)*128); coalesced lane reads
        const float f0 = fsh[lane], f1 = fsh[64 + lane];
        for (int r = 0; r < 128; ++r) {
            const int o = wv * 128 + r;
            const float* wr = &W2[(size_t)o * 128];
            float part = wr[lane] * f0 + wr[64 + lane] * f1;
#pragma unroll
            for (int s = 1; s < 64; s <<= 1) part += __shfl_xor(part, s);
            if (lane == 0) {
                const float s = g2[o] / sqrtf(v2[o] + EPSC);
                hsh[o] = fmaxf(part * s + (b2[o] - m2[o] * s), 0.f);
            }
        }
        __syncthreads();
        // W3 pass: wave w -> rows [w*32, (w+1)*32); 8 coalesced segments
        for (int r = 0; r < 32; ++r) {
            const int o = wv * 32 + r;
            const float* wr = &W3[(size_t)o * 512];
            float part = 0.f;
#pragma unroll
            for (int s8 = 0; s8 < 8; ++s8)
                part = fmaf(wr[s8 * 64 + lane], hsh[s8 * 64 + lane], part);
#pragma unroll
            for (int s = 1; s < 64; s <<= 1) part += __shfl_xor(part, s);
            if (lane == 0) {
                const float s = g3[o] / sqrtf(v3[o] + EPSC);
                const float e = fmaxf(part * s + (b3[o] - m3[o] * s)
                                      + x[(size_t)p * 128 + o], 0.f);
                const float cur = y_out[(size_t)p * 128 + o];
                y_out[(size_t)p * 128 + o] = 0.5f * (cur + e);
            }
        }
    }
}

// ---------------------------------------------------------------------------
extern "C" void kernel_launch(void* const* d_in, const int* in_sizes, int n_in,
                              void* d_out, int out_size, void* d_ws, size_t ws_size,
                              hipStream_t stream)
{
    const float* pos = (const float*)d_in[0];
    const float* x   = (const float*)d_in[1];
    const float* W1  = (const float*)d_in[2];
    const float* g1  = (const float*)d_in[3];
    const float* b1  = (const float*)d_in[4];
    const float* m1  = (const float*)d_in[5];
    const float* v1  = (const float*)d_in[6];
    const float* W2  = (const float*)d_in[7];
    const float* g2  = (const float*)d_in[8];
    const float* b2  = (const float*)d_in[9];
    const float* m2  = (const float*)d_in[10];
    const float* v2  = (const float*)d_in[11];
    const float* W3  = (const float*)d_in[12];
    const float* g3  = (const float*)d_in[13];
    const float* b3  = (const float*)d_in[14];
    const float* m3  = (const float*)d_in[15];
    const float* v3  = (const float*)d_in[16];

    float* out = (float*)d_out;
    float* pos_out = out;                     // 8*4096*3 floats
    float* y_out   = out + 98304;             // 8*4096*128 floats

    char* ws = (char*)d_ws;
    int*   idx_inc = (int*)ws;                                    // 4 MB @ 0
    int*   idx_exc = (int*)(ws + ((size_t)4  << 20));             // 4 MB @ 4M
    int*   flags   = (int*)(ws + ((size_t)8  << 20));             // 128 KB @ 8M
    u16*   W2h     = (u16*)(ws + ((size_t)8  << 20) + (128u<<10));// 128 KB
    u16*   W2l     = (u16*)(ws + ((size_t)8  << 20) + (256u<<10));// 128 KB
    u16*   W3h     = (u16*)(ws + ((size_t)8  << 20) + (384u<<10));// 128 KB
    u16*   W3l     = (u16*)(ws + ((size_t)8  << 20) + (512u<<10));// 128 KB
    u16*   W1h     = (u16*)(ws + ((size_t)8  << 20) + (640u<<10));// 32 KB
    u16*   W1l     = (u16*)(ws + ((size_t)8  << 20) + (704u<<10));// 32 KB
    float* xws     = (float*)(ws + ((size_t)9  << 20));           // 16 MB @ 9M
    u16*   fh      = (u16*)(ws + ((size_t)25 << 20));             // 8 MB @ 25M
    u16*   fl      = (u16*)(ws + ((size_t)33 << 20));             // 8 MB @ 33M
    float* f_exc   = (float*)(ws + ((size_t)41 << 20));           // 16 MB @ 41M
    u16*   hh      = (u16*)(ws + ((size_t)57 << 20));             // 32 MB @ 57M
    u16*   hl      = (u16*)(ws + ((size_t)89 << 20));             // 32 MB @ 89M
    int*   gsorted = (int*)(ws + ((size_t)121 << 20));            // 128 KB @ 121M
    int*   gstarts = (int*)(ws + ((size_t)121 << 20) + (512u<<10)); // 7 KB
    (void)ws_size; (void)in_sizes; (void)n_in; (void)out_size;

    // P: weight splits
    split_w1_kernel<<<64, 256, 0, stream>>>(W1, W1h, W1l);
    split_kernel<<<256, 256, 0, stream>>>(W2, W2h, W2l, 512 * 128);
    split_kernel<<<256, 256, 0, stream>>>(W3, W3h, W3l, 128 * 512);
    // G: per-batch grid build + pos passthrough
    grid_build_kernel<<<8, 1024, 0, stream>>>(pos, gsorted, gstarts, pos_out);
    // A: grid-pruned ball query (bitmap selection)
    ball_query_kernel<<<512, 1024, 0, stream>>>(
        pos, gsorted, gstarts, idx_inc, idx_exc, flags);
    // B: xws = (x @ W1[:,3:].T) * s1   [MFMA, BM=64, fused x-conversion]
    mfma_gemm_kernel<64, 128, 0, true><<<dim3(512, 1), 256, 0, stream>>>(
        nullptr, nullptr, x, W1h, W1l, g1, b1, m1, v1, nullptr, nullptr, nullptr, xws, 128);
    // C: gather + max-pool, 4 pts/wave in GRID-SORTED order [XCD-swz]
    group_max_kernel<<<2048, 256, 0, stream>>>(
        pos, gsorted, idx_inc, idx_exc, flags, xws, W1, g1, b1, m1, v1, fh, fl, f_exc);
    // D1: (hh,hl) = split(relu(bn2(f @ W2^T)))  [MFMA, BM=64]
    mfma_gemm_kernel<64, 128, 1, false><<<dim3(512, 4), 256, 0, stream>>>(
        fh, fl, nullptr, W2h, W2l, g2, b2, m2, v2, nullptr, hh, hl, nullptr, 512);
    // D2: y = relu(x + bn3(h @ W3^T))           [MFMA, BM=64]
    mfma_gemm_kernel<64, 512, 2, false><<<dim3(512, 1), 256, 0, stream>>>(
        hh, hl, nullptr, W3h, W3l, g3, b3, m3, v3, x, nullptr, nullptr, y_out, 128);
    // E: flagged points -> coalesced wave-reduction midpoint fixup
    fixup_kernel<<<8192, 256, 0, stream>>>(
        flags, f_exc, x, W2, g2, b2, m2, v2, W3, g3, b3, m3, v3, y_out);
}

// Round 33
// 173.794 us; speedup vs baseline: 1.5043x; 1.5043x over previous
//
#include <hip/hip_runtime.h>
#include <cstdint>
#include <cstddef>

#define NPTS 4096
#define KNB 32
#define EPSC 1e-5f
#define NC 6            // grid cells per axis (1/6 = 0.1667 >= 0.15 ball radius)
#define NCELL (NC*NC*NC)
#define CAPF 512        // max flagged points routed through dense fixup GEMM

typedef short short8v __attribute__((ext_vector_type(8)));
typedef float f32x4 __attribute__((ext_vector_type(4)));
typedef unsigned short u16;

__device__ __forceinline__ u16 f2bf(float x) {
    unsigned u = __float_as_uint(x);
    u = (u + 0x7FFFu + ((u >> 16) & 1u)) >> 16;
    return (u16)u;
}
__device__ __forceinline__ float bf2f(u16 h) {
    return __uint_as_float((unsigned)h << 16);
}

// ---------------------------------------------------------------------------
// splits: f32 -> (bf16 hi, bf16 lo)
// ---------------------------------------------------------------------------
__global__ __launch_bounds__(256) void split_kernel(
    const float* __restrict__ src, u16* __restrict__ hi, u16* __restrict__ lo, int n)
{
    int i = blockIdx.x * 256 + threadIdx.x;
    if (i < n) {
        float v = src[i];
        u16 h = f2bf(v);
        hi[i] = h;
        lo[i] = f2bf(v - bf2f(h));
    }
}
__global__ __launch_bounds__(256) void split_w1_kernel(
    const float* __restrict__ W1, u16* __restrict__ hi, u16* __restrict__ lo)
{
    int i = blockIdx.x * 256 + threadIdx.x;      // 16384
    int n = i >> 7, k = i & 127;
    float v = W1[n * 131 + 3 + k];
    u16 h = f2bf(v);
    hi[i] = h;
    lo[i] = f2bf(v - bf2f(h));
}

// ---------------------------------------------------------------------------
// Kernel G: per-batch grid build (counting sort) + pos passthrough.
// ---------------------------------------------------------------------------
__global__ __launch_bounds__(1024) void grid_build_kernel(
    const float* __restrict__ pos, int* __restrict__ gsorted,
    int* __restrict__ gstarts, float* __restrict__ pos_out)
{
    __shared__ int cnt[NCELL];
    __shared__ int st[NCELL + 1];
    const int b = blockIdx.x;
    const int tid = threadIdx.x;
    const float* pb = pos + (size_t)b * NPTS * 3;

    for (int c = tid; c < NCELL; c += 1024) cnt[c] = 0;
    __syncthreads();
    for (int j = tid; j < NPTS; j += 1024) {
        const float x = pb[j*3+0], y = pb[j*3+1], z = pb[j*3+2];
        int ix = (int)(x * 6.0f); ix = ix > 5 ? 5 : ix;
        int iy = (int)(y * 6.0f); iy = iy > 5 ? 5 : iy;
        int iz = (int)(z * 6.0f); iz = iz > 5 ? 5 : iz;
        atomicAdd(&cnt[(iz * NC + iy) * NC + ix], 1);
    }
    {   // pos passthrough
        const float4* src = (const float4*)pb;
        float4* dst = (float4*)(pos_out + (size_t)b * NPTS * 3);
        for (int i = tid; i < NPTS * 3 / 4; i += 1024) dst[i] = src[i];
    }
    __syncthreads();
    if (tid == 0) {
        int a = 0;
        for (int c = 0; c < NCELL; ++c) { st[c] = a; a += cnt[c]; }
        st[NCELL] = a;
    }
    __syncthreads();
    for (int c = tid; c < NCELL + 1; c += 1024) gstarts[b * (NCELL + 1) + c] = st[c];
    for (int c = tid; c < NCELL; c += 1024) cnt[c] = 0;
    __syncthreads();
    for (int j = tid; j < NPTS; j += 1024) {
        const float x = pb[j*3+0], y = pb[j*3+1], z = pb[j*3+2];
        int ix = (int)(x * 6.0f); ix = ix > 5 ? 5 : ix;
        int iy = (int)(y * 6.0f); iy = iy > 5 ? 5 : iy;
        int iz = (int)(z * 6.0f); iz = iz > 5 ? 5 : iz;
        const int cid = (iz * NC + iy) * NC + ix;
        const int slot = st[cid] + atomicAdd(&cnt[cid], 1);
        gsorted[b * NPTS + slot] = j;
    }
}

// ---------------------------------------------------------------------------
// Kernel A: grid-pruned ball query with BITMAP selection (r28).
// ---------------------------------------------------------------------------
__device__ __forceinline__ int wave_min64(int m) {
#pragma unroll
    for (int s = 1; s < 64; s <<= 1) {
        const int o = __shfl_xor(m, s);
        m = m < o ? m : o;
    }
    return m;
}

template<bool BAND>
__device__ __forceinline__ int gather_bits(
    const float4* __restrict__ spos, const int* __restrict__ sst,
    unsigned* __restrict__ bm,
    float px, float py, float pz, int lane, float thr, float tlo)
{
    bm[lane] = 0u; bm[64 + lane] = 0u;               // zero wave-private bitmap
    int cxi = (int)(px * 6.0f); cxi = cxi > 5 ? 5 : cxi;
    int cyi = (int)(py * 6.0f); cyi = cyi > 5 ? 5 : cyi;
    int czi = (int)(pz * 6.0f); czi = czi > 5 ? 5 : czi;
    const int x0 = cxi > 0 ? cxi - 1 : 0, x1 = cxi < 5 ? cxi + 1 : 5;
    const int y0 = cyi > 0 ? cyi - 1 : 0, y1 = cyi < 5 ? cyi + 1 : 5;
    const int z0 = czi > 0 ? czi - 1 : 0, z1 = czi < 5 ? czi + 1 : 5;
    int anyband = 0;
    for (int zz = z0; zz <= z1; ++zz)
    for (int yy = y0; yy <= y1; ++yy) {
        const int cb = (zz * NC + yy) * NC;
        const int s = sst[cb + x0];
        const int e = sst[cb + x1 + 1];
        for (int off = s; off < e; off += 64) {
            const int ii = off + lane;
            bool hit = false, band = false;
            int j = 0;
            if (ii < e) {
                const float4 c = spos[ii];
                const float dx = px - c.x;
                const float dy = py - c.y;
                const float dz = pz - c.z;
                const float d2 = fmaf(dx, dx, fmaf(dy, dy, dz * dz));
                hit = d2 < thr;
                band = BAND && hit && !(d2 < tlo);
                j = __float_as_int(c.w);
            }
            if (BAND)
                anyband |= (__ballot(band) != 0ull) ? 1 : 0;
            if (hit)
                atomicOr(&bm[j >> 5], 1u << (j & 31));
        }
    }
    return anyband;
}

__device__ __forceinline__ void select32_bitmap(
    const unsigned* __restrict__ bm, int lane, int* __restrict__ outp)
{
    unsigned w0 = bm[2 * lane], w1 = bm[2 * lane + 1];
    const int c = __popc(w0) + __popc(w1);
    int pre = c;                                     // inclusive prefix sum
#pragma unroll
    for (int s = 1; s < 64; s <<= 1) {
        const int o = __shfl_up(pre, s);
        if (lane >= s) pre += o;
    }
    const int total = __shfl(pre, 63);
    int r = pre - c;                                 // exclusive prefix
    int myfirst = 0x7FFFFFFF;
    if (w0) myfirst = lane * 64 + (__ffs(w0) - 1);
    else if (w1) myfirst = lane * 64 + 32 + (__ffs(w1) - 1);
    const int firstj = wave_min64(myfirst);          // smallest hit index
    const int base = lane * 64;
    while (w0 && r < KNB) {
        const int bpos = __ffs(w0) - 1;
        outp[r++] = base + bpos;
        w0 &= w0 - 1;
    }
    while (w1 && r < KNB) {
        const int bpos = __ffs(w1) - 1;
        outp[r++] = base + 32 + bpos;
        w1 &= w1 - 1;
    }
    const int stored = total < KNB ? total : KNB;
    if (lane >= stored && lane < KNB) outp[lane] = firstj;   // pad w/ first hit
}

__global__ __launch_bounds__(1024) void ball_query_kernel(
    const float* __restrict__ pos, const int* __restrict__ gsorted,
    const int* __restrict__ gstarts,
    int* __restrict__ idx_inc, int* __restrict__ idx_exc,
    int* __restrict__ flags)
{
    __shared__ float4 spos[NPTS];                    // 64 KB, sorted order
    __shared__ int sst[NCELL + 2];
    __shared__ unsigned bmap[16][128];               // 8 KB (wave-private)
    const int tid  = threadIdx.x;
    const int lane = tid & 63;
    const int wv   = tid >> 6;
    const int pbase = blockIdx.x * 64;               // 64 points per block
    const int b = pbase >> 12;
    const float* pb = pos + (size_t)b * NPTS * 3;

    const float T_HI = (float)(0.0225 + 3e-7);
    const float T_LO = (float)(0.0225 - 3e-7);

    for (int i = tid; i < NPTS; i += 1024) {
        const int j = gsorted[b * NPTS + i];
        spos[i] = make_float4(pb[j*3+0], pb[j*3+1], pb[j*3+2],
                              __int_as_float(j));
    }
    if (tid < NCELL + 1) sst[tid] = gstarts[b * (NCELL + 1) + tid];
    __syncthreads();

    unsigned* bm = bmap[wv];
    for (int pi = 0; pi < 4; ++pi) {
        const int p = pbase + wv * 4 + pi;
        const int ml = p & (NPTS - 1);
        const float px = pb[ml*3+0], py = pb[ml*3+1], pz = pb[ml*3+2];
        const int flg = gather_bits<true>(spos, sst, bm, px, py, pz,
                                          lane, T_HI, T_LO);
        select32_bitmap(bm, lane, idx_inc + (size_t)p * KNB);
        if (flg) {                                   // rare, wave-uniform
            gather_bits<false>(spos, sst, bm, px, py, pz, lane, T_LO, T_LO);
            select32_bitmap(bm, lane, idx_exc + (size_t)p * KNB);
        }
        if (lane == 0) flags[p] = flg;
    }
}

// ---------------------------------------------------------------------------
// Fixup slot machinery: init, compact (flagged point -> dense slot).
// Slot assignment order is nondeterministic (atomicAdd) but each point's
// result depends only on its own data -> output deterministic.
// ---------------------------------------------------------------------------
__global__ __launch_bounds__(256) void fixup_init_kernel(
    int* __restrict__ counter, int* __restrict__ map, int* __restrict__ slotof)
{
    const int i = blockIdx.x * 256 + threadIdx.x;    // grid covers 32768
    if (i == 0) *counter = 0;
    if (i < CAPF) map[i] = -1;
    slotof[i] = -1;
}
__global__ __launch_bounds__(256) void fixup_compact_kernel(
    const int* __restrict__ flags, int* __restrict__ counter,
    int* __restrict__ map, int* __restrict__ slotof)
{
    const int p = blockIdx.x * 256 + threadIdx.x;
    if (flags[p]) {
        const int s = atomicAdd(counter, 1);
        if (s < CAPF) { map[s] = p; slotof[p] = s; }
    }
}

// ---------------------------------------------------------------------------
// MFMA split-bf16 GEMM, BM x 128 tile, register double-buffer prefetch (r24).
// CVTA: A is f32, converted during staging.
// EPI 0: y=acc*s (f32). EPI 1: relu -> split store. EPI 2: relu(X+...) f32.
// EPI 3: acc*s + t (bias, NO relu, NO X) f32 -- fixup pre-residual output.
// ---------------------------------------------------------------------------
template<int BM, int KTOT, bool CVTA>
__device__ __forceinline__ void mfma_load_chunk(
    const u16* __restrict__ Ahg, const u16* __restrict__ Alg,
    const float* __restrict__ Af32,
    const u16* __restrict__ Whg, const u16* __restrict__ Wlg,
    int rowbase, int colbase, int arow, int ak, int brow, int bk, int kc,
    short8v* pAh, short8v* pAl, short8v* pBh, short8v* pBl)
{
    constexpr int APT = BM / 8;
    constexpr int NSEG = APT / 8;
    const size_t ga = (size_t)(rowbase + arow) * KTOT + kc * 32 + ak;
    if constexpr (CVTA) {
        float vals[APT];
#pragma unroll
        for (int s4 = 0; s4 < APT / 4; ++s4)
            *(float4*)&vals[s4 * 4] = *(const float4*)&Af32[ga + s4 * 4];
        u16 hi16[APT], lo16[APT];
#pragma unroll
        for (int i = 0; i < APT; ++i) {
            const u16 h = f2bf(vals[i]);
            hi16[i] = h;
            lo16[i] = f2bf(vals[i] - bf2f(h));
        }
#pragma unroll
        for (int s = 0; s < NSEG; ++s) {
            pAh[s] = *(const short8v*)&hi16[s * 8];
            pAl[s] = *(const short8v*)&lo16[s * 8];
        }
    } else {
#pragma unroll
        for (int s = 0; s < NSEG; ++s) {
            pAh[s] = *(const short8v*)&Ahg[ga + s * 8];
            pAl[s] = *(const short8v*)&Alg[ga + s * 8];
        }
    }
    const size_t gw = (size_t)(colbase + brow) * KTOT + kc * 32 + bk;
    pBh[0] = *(const short8v*)&Whg[gw];
    pBh[1] = *(const short8v*)&Whg[gw + 8];
    pBl[0] = *(const short8v*)&Wlg[gw];
    pBl[1] = *(const short8v*)&Wlg[gw + 8];
}

template<int BM, int KTOT, int EPI, bool CVTA>
__global__ __launch_bounds__(256) void mfma_gemm_kernel(
    const u16* __restrict__ Ahg, const u16* __restrict__ Alg,
    const float* __restrict__ Af32,
    const u16* __restrict__ Whg, const u16* __restrict__ Wlg,
    const float* __restrict__ gg, const float* __restrict__ bb,
    const float* __restrict__ mm, const float* __restrict__ vv,
    const float* __restrict__ X,
    u16* __restrict__ Oh, u16* __restrict__ Ol,
    float* __restrict__ Yf, int nstride)
{
    constexpr int MI   = BM / 32;    // 16-row frags per wave
    constexpr int APT  = BM / 8;     // A u16 per thread per array
    constexpr int NSEG = APT / 8;
    constexpr int NK   = KTOT / 32;
    __shared__ u16 Ah[BM][40];
    __shared__ u16 Al[BM][40];
    __shared__ u16 Bh[128][40];
    __shared__ u16 Bl[128][40];
    const int tid  = threadIdx.x;
    const int lane = tid & 63;
    const int wv   = tid >> 6;
    const int rowbase = blockIdx.x * BM;
    const int colbase = blockIdx.y * 128;
    const int R0 = (wv >> 1) * (BM / 2);
    const int C0 = (wv & 1) * 64;
    const int aoff = tid * APT;
    const int arow = aoff >> 5;
    const int ak   = aoff & 31;
    const int brow = tid >> 1;
    const int bk   = (tid & 1) * 16;
    const int fr = lane & 15;
    const int fq = lane >> 4;

    f32x4 acc[MI][4];
#pragma unroll
    for (int i = 0; i < MI; ++i)
#pragma unroll
        for (int j = 0; j < 4; ++j)
            acc[i][j] = (f32x4){0.f, 0.f, 0.f, 0.f};

    short8v pAh[NSEG], pAl[NSEG], pBh[2], pBl[2];
    mfma_load_chunk<BM, KTOT, CVTA>(Ahg, Alg, Af32, Whg, Wlg,
        rowbase, colbase, arow, ak, brow, bk, 0, pAh, pAl, pBh, pBl);

    for (int kc = 0; kc < NK; ++kc) {
        __syncthreads();                 // prior compute done reading LDS
#pragma unroll
        for (int s = 0; s < NSEG; ++s) {
            *(short8v*)&Ah[arow][ak + s * 8] = pAh[s];
            *(short8v*)&Al[arow][ak + s * 8] = pAl[s];
        }
        *(short8v*)&Bh[brow][bk]     = pBh[0];
        *(short8v*)&Bh[brow][bk + 8] = pBh[1];
        *(short8v*)&Bl[brow][bk]     = pBl[0];
        *(short8v*)&Bl[brow][bk + 8] = pBl[1];
        if (kc + 1 < NK)                 // prefetch next chunk (latency hidden)
            mfma_load_chunk<BM, KTOT, CVTA>(Ahg, Alg, Af32, Whg, Wlg,
                rowbase, colbase, arow, ak, brow, bk, kc + 1, pAh, pAl, pBh, pBl);
        __syncthreads();

        short8v ahf[MI], alf[MI];
#pragma unroll
        for (int fi = 0; fi < MI; ++fi) {
            ahf[fi] = *(const short8v*)&Ah[R0 + fi * 16 + fr][fq * 8];
            alf[fi] = *(const short8v*)&Al[R0 + fi * 16 + fr][fq * 8];
        }
#pragma unroll
        for (int fj = 0; fj < 4; ++fj) {
            const short8v bh = *(const short8v*)&Bh[C0 + fj * 16 + fr][fq * 8];
            const short8v bl = *(const short8v*)&Bl[C0 + fj * 16 + fr][fq * 8];
#pragma unroll
            for (int fi = 0; fi < MI; ++fi) {
                acc[fi][fj] = __builtin_amdgcn_mfma_f32_16x16x32_bf16(ahf[fi], bh, acc[fi][fj], 0, 0, 0);
                acc[fi][fj] = __builtin_amdgcn_mfma_f32_16x16x32_bf16(ahf[fi], bl, acc[fi][fj], 0, 0, 0);
                acc[fi][fj] = __builtin_amdgcn_mfma_f32_16x16x32_bf16(alf[fi], bh, acc[fi][fj], 0, 0, 0);
            }
        }
    }

    // epilogue: D mapping row=(lane>>4)*4+reg, col=lane&15  [m89 verified]
#pragma unroll
    for (int fj = 0; fj < 4; ++fj) {
        const int col = colbase + C0 + fj * 16 + fr;
        const float sc = gg[col] / sqrtf(vv[col] + EPSC);
        const float tt = (EPI == 0) ? 0.f : (bb[col] - mm[col] * sc);
#pragma unroll
        for (int fi = 0; fi < MI; ++fi) {
#pragma unroll
            for (int r = 0; r < 4; ++r) {
                const int row = rowbase + R0 + fi * 16 + fq * 4 + r;
                float v = acc[fi][fj][r] * sc + tt;
                if (EPI == 2) v += X[(size_t)row * 128 + col];
                if (EPI == 1 || EPI == 2) v = fmaxf(v, 0.f);
                if (EPI == 1) {
                    const u16 h = f2bf(v);
                    Oh[(size_t)row * nstride + col] = h;
                    Ol[(size_t)row * nstride + col] = f2bf(v - bf2f(h));
                } else {
                    Yf[(size_t)row * nstride + col] = v;
                }
            }
        }
    }
}

// ---------------------------------------------------------------------------
// Kernel C: gather + rel contribution + max-pool, 4 pts/wave, grid-sorted
// order (r30). Exc rows go DIRECTLY to the dense fixup buffer as bf16 hi/lo
// (slotof[p] >= 0 iff flagged and within capacity).
// XCD-affine swizzle: 256 blocks/batch on one XCD.
// ---------------------------------------------------------------------------
__global__ __launch_bounds__(256) void group_max_kernel(
    const float* __restrict__ pos, const int* __restrict__ gsorted,
    const int* __restrict__ idx_inc, const int* __restrict__ idx_exc,
    const int* __restrict__ slotof, const float* __restrict__ xws,
    const float* __restrict__ W1, const float* __restrict__ g1,
    const float* __restrict__ b1, const float* __restrict__ m1,
    const float* __restrict__ v1,
    u16* __restrict__ fh, u16* __restrict__ fl,
    u16* __restrict__ fdh, u16* __restrict__ fdl)
{
    __shared__ float4 relbuf [4][4][KNB];            // inc tables: 8 KB
    __shared__ float4 relbuf2[4][4][KNB];            // exc tables: 8 KB
    const int tid  = threadIdx.x;
    const int lane = tid & 63;
    const int wv   = tid >> 6;
    const int bid  = blockIdx.x;                     // 0..2047
    const int grp  = (bid & 7) * 256 + (bid >> 3);   // XCD-affine, bijective
    const int b = grp >> 8;                          // batch (256 blocks/batch)
    const int spos0 = (grp & 255) * 16 + wv * 4;     // sorted position of pt 0
    const float* pb = pos + (size_t)b * NPTS * 3;
    const char* xws_b = (const char*)(xws + (size_t)b * NPTS * 128);
    const int o0 = lane * 2;
    const int lane8 = lane * 8;

    const float w00 = W1[(size_t)o0*131+0], w01 = W1[(size_t)o0*131+1], w02 = W1[(size_t)o0*131+2];
    const float w10 = W1[(size_t)(o0+1)*131+0], w11 = W1[(size_t)(o0+1)*131+1], w12 = W1[(size_t)(o0+1)*131+2];
    const float s0 = g1[o0]   / sqrtf(v1[o0]   + EPSC);
    const float s1 = g1[o0+1] / sqrtf(v1[o0+1] + EPSC);
    const float t0 = b1[o0]   - m1[o0]   * s0;
    const float t1 = b1[o0+1] - m1[o0+1] * s1;
    const float q00 = w00*s0, q01 = w01*s0, q02 = w02*s0;
    const float q10 = w10*s1, q11 = w11*s1, q12 = w12*s1;

    int pact[4], st[4];
#pragma unroll
    for (int t = 0; t < 4; ++t) {
        const int ml = gsorted[b * NPTS + spos0 + t];     // wave-uniform
        pact[t] = b * NPTS + ml;                          // actual point id
        st[t] = slotof[pact[t]];                          // >=0 iff flagged
    }

    // preload 4 inc (and rare exc) tables: 128 entries over 64 lanes, 2 passes
#pragma unroll
    for (int rep = 0; rep < 2; ++rep) {
        const int g = rep * 64 + lane;
        const int t = g >> 5, slot = g & 31;
        const int pq = pact[t];
        const int ml = pq & (NPTS - 1);
        const float cx = pb[ml*3+0], cy = pb[ml*3+1], cz = pb[ml*3+2];
        const int j = idx_inc[(size_t)pq * KNB + slot];
        const float* pj = &pb[j*3];
        relbuf[wv][t][slot] = make_float4(
            (pj[0]-cx)/0.15f, (pj[1]-cy)/0.15f, (pj[2]-cz)/0.15f,
            __int_as_float(j << 9));
        if (st[t] >= 0) {
            const int je = idx_exc[(size_t)pq * KNB + slot];
            const float* pe = &pb[je*3];
            relbuf2[wv][t][slot] = make_float4(
                (pe[0]-cx)/0.15f, (pe[1]-cy)/0.15f, (pe[2]-cz)/0.15f,
                __int_as_float(je << 9));
        }
    }
    __syncthreads();

    {   // interleaved quad-point max-pool (4 loads in flight per k)
        float acc0[4], acc1[4];
#pragma unroll
        for (int t = 0; t < 4; ++t) { acc0[t] = 0.f; acc1[t] = 0.f; }
#pragma unroll 4
        for (int k = 0; k < KNB; ++k) {
            float4 rv[4];
#pragma unroll
            for (int t = 0; t < 4; ++t) rv[t] = relbuf[wv][t][k];
            float2 xw[4];
#pragma unroll
            for (int t = 0; t < 4; ++t)
                xw[t] = *(const float2*)(xws_b + __float_as_int(rv[t].w) + lane8);
#pragma unroll
            for (int t = 0; t < 4; ++t) {
                acc0[t] = fmaxf(acc0[t], fmaf(rv[t].x, q00, fmaf(rv[t].y, q01, fmaf(rv[t].z, q02, t0 + xw[t].x))));
                acc1[t] = fmaxf(acc1[t], fmaf(rv[t].x, q10, fmaf(rv[t].y, q11, fmaf(rv[t].z, q12, t1 + xw[t].y))));
            }
        }
#pragma unroll
        for (int t = 0; t < 4; ++t) {
            const u16 h0 = f2bf(acc0[t]); const u16 l0 = f2bf(acc0[t] - bf2f(h0));
            const u16 h1 = f2bf(acc1[t]); const u16 l1 = f2bf(acc1[t] - bf2f(h1));
            *(unsigned*)&fh[(size_t)pact[t] * 128 + o0] = (unsigned)h0 | ((unsigned)h1 << 16);
            *(unsigned*)&fl[(size_t)pact[t] * 128 + o0] = (unsigned)l0 | ((unsigned)l1 << 16);
        }
    }
#pragma unroll
    for (int t = 0; t < 4; ++t) {
        if (st[t] >= 0) {                            // rare, wave-uniform
            const float4* rt = relbuf2[wv][t];
            float e0 = 0.f, e1 = 0.f;
#pragma unroll 8
            for (int k = 0; k < KNB; ++k) {
                const float4 rv = rt[k];
                const float2 xw = *(const float2*)(xws_b + __float_as_int(rv.w) + lane8);
                e0 = fmaxf(e0, fmaf(rv.x, q00, fmaf(rv.y, q01, fmaf(rv.z, q02, t0 + xw.x))));
                e1 = fmaxf(e1, fmaf(rv.x, q10, fmaf(rv.y, q11, fmaf(rv.z, q12, t1 + xw.y))));
            }
            const u16 h0 = f2bf(e0); const u16 l0 = f2bf(e0 - bf2f(h0));
            const u16 h1 = f2bf(e1); const u16 l1 = f2bf(e1 - bf2f(h1));
            *(unsigned*)&fdh[(size_t)st[t] * 128 + o0] = (unsigned)h0 | ((unsigned)h1 << 16);
            *(unsigned*)&fdl[(size_t)st[t] * 128 + o0] = (unsigned)l0 | ((unsigned)l1 << 16);
        }
    }
}

// ---------------------------------------------------------------------------
// Kernel F: blend — e = relu(ydense + x[p]); y_out[p] = midpoint.
// ---------------------------------------------------------------------------
__global__ __launch_bounds__(128) void fixup_blend_kernel(
    const int* __restrict__ map, const float* __restrict__ ydense,
    const float* __restrict__ x, float* __restrict__ y_out)
{
    const int s = blockIdx.x;
    const int o = threadIdx.x;
    const int p = map[s];
    if (p < 0) return;
    const float e = fmaxf(ydense[(size_t)s * 128 + o] + x[(size_t)p * 128 + o], 0.f);
    const float cur = y_out[(size_t)p * 128 + o];
    y_out[(size_t)p * 128 + o] = 0.5f * (cur + e);
}

// ---------------------------------------------------------------------------
extern "C" void kernel_launch(void* const* d_in, const int* in_sizes, int n_in,
                              void* d_out, int out_size, void* d_ws, size_t ws_size,
                              hipStream_t stream)
{
    const float* pos = (const float*)d_in[0];
    const float* x   = (const float*)d_in[1];
    const float* W1  = (const float*)d_in[2];
    const float* g1  = (const float*)d_in[3];
    const float* b1  = (const float*)d_in[4];
    const float* m1  = (const float*)d_in[5];
    const float* v1  = (const float*)d_in[6];
    const float* W2  = (const float*)d_in[7];
    const float* g2  = (const float*)d_in[8];
    const float* b2  = (const float*)d_in[9];
    const float* m2  = (const float*)d_in[10];
    const float* v2  = (const float*)d_in[11];
    const float* W3  = (const float*)d_in[12];
    const float* g3  = (const float*)d_in[13];
    const float* b3  = (const float*)d_in[14];
    const float* m3  = (const float*)d_in[15];
    const float* v3  = (const float*)d_in[16];

    float* out = (float*)d_out;
    float* pos_out = out;                     // 8*4096*3 floats
    float* y_out   = out + 98304;             // 8*4096*128 floats

    char* ws = (char*)d_ws;
    int*   idx_inc = (int*)ws;                                    // 4 MB @ 0
    int*   idx_exc = (int*)(ws + ((size_t)4  << 20));             // 4 MB @ 4M
    int*   flags   = (int*)(ws + ((size_t)8  << 20));             // 128 KB @ 8M
    u16*   W2h     = (u16*)(ws + ((size_t)8  << 20) + (128u<<10));// 128 KB
    u16*   W2l     = (u16*)(ws + ((size_t)8  << 20) + (256u<<10));// 128 KB
    u16*   W3h     = (u16*)(ws + ((size_t)8  << 20) + (384u<<10));// 128 KB
    u16*   W3l     = (u16*)(ws + ((size_t)8  << 20) + (512u<<10));// 128 KB
    u16*   W1h     = (u16*)(ws + ((size_t)8  << 20) + (640u<<10));// 32 KB
    u16*   W1l     = (u16*)(ws + ((size_t)8  << 20) + (704u<<10));// 32 KB
    float* xws     = (float*)(ws + ((size_t)9  << 20));           // 16 MB @ 9M
    u16*   fh      = (u16*)(ws + ((size_t)25 << 20));             // 8 MB @ 25M
    u16*   fl      = (u16*)(ws + ((size_t)33 << 20));             // 8 MB @ 33M
    // fixup dense buffers (in old f_exc region @ 41M)
    int*   slotof  = (int*)(ws + ((size_t)41 << 20));             // 128 KB
    int*   fmap    = (int*)(ws + ((size_t)41 << 20) + (128u<<10));// 2 KB
    int*   fcnt    = (int*)(ws + ((size_t)41 << 20) + (192u<<10));// 4 B
    u16*   fdh     = (u16*)(ws + ((size_t)41 << 20) + (256u<<10));// 128 KB
    u16*   fdl     = (u16*)(ws + ((size_t)41 << 20) + (384u<<10));// 128 KB
    u16*   hdh     = (u16*)(ws + ((size_t)42 << 20));             // 512 KB
    u16*   hdl     = (u16*)(ws + ((size_t)42 << 20) + (512u<<10));// 512 KB
    float* ydense  = (float*)(ws + ((size_t)43 << 20));           // 256 KB
    u16*   hh      = (u16*)(ws + ((size_t)57 << 20));             // 32 MB @ 57M
    u16*   hl      = (u16*)(ws + ((size_t)89 << 20));             // 32 MB @ 89M
    int*   gsorted = (int*)(ws + ((size_t)121 << 20));            // 128 KB @ 121M
    int*   gstarts = (int*)(ws + ((size_t)121 << 20) + (512u<<10)); // 7 KB
    (void)ws_size; (void)in_sizes; (void)n_in; (void)out_size;

    // P: weight splits
    split_w1_kernel<<<64, 256, 0, stream>>>(W1, W1h, W1l);
    split_kernel<<<256, 256, 0, stream>>>(W2, W2h, W2l, 512 * 128);
    split_kernel<<<256, 256, 0, stream>>>(W3, W3h, W3l, 128 * 512);
    // G: per-batch grid build + pos passthrough
    grid_build_kernel<<<8, 1024, 0, stream>>>(pos, gsorted, gstarts, pos_out);
    // A: grid-pruned ball query (bitmap selection)
    ball_query_kernel<<<512, 1024, 0, stream>>>(
        pos, gsorted, gstarts, idx_inc, idx_exc, flags);
    // F0/F1: slot init + compaction of flagged points
    fixup_init_kernel<<<128, 256, 0, stream>>>(fcnt, fmap, slotof);
    fixup_compact_kernel<<<128, 256, 0, stream>>>(flags, fcnt, fmap, slotof);
    // B: xws = (x @ W1[:,3:].T) * s1   [MFMA, BM=64, fused x-conversion]
    mfma_gemm_kernel<64, 128, 0, true><<<dim3(512, 1), 256, 0, stream>>>(
        nullptr, nullptr, x, W1h, W1l, g1, b1, m1, v1, nullptr, nullptr, nullptr, xws, 128);
    // C: gather + max-pool, 4 pts/wave, grid-sorted [XCD-swz]; exc -> dense
    group_max_kernel<<<2048, 256, 0, stream>>>(
        pos, gsorted, idx_inc, idx_exc, slotof, xws, W1, g1, b1, m1, v1,
        fh, fl, fdh, fdl);
    // D1: (hh,hl) = split(relu(bn2(f @ W2^T)))  [MFMA, BM=64]
    mfma_gemm_kernel<64, 128, 1, false><<<dim3(512, 4), 256, 0, stream>>>(
        fh, fl, nullptr, W2h, W2l, g2, b2, m2, v2, nullptr, hh, hl, nullptr, 512);
    // D2: y = relu(x + bn3(h @ W3^T))           [MFMA, BM=64]
    mfma_gemm_kernel<64, 512, 2, false><<<dim3(512, 1), 256, 0, stream>>>(
        hh, hl, nullptr, W3h, W3l, g3, b3, m3, v3, x, nullptr, nullptr, y_out, 128);
    // D1f/D2f: dense fixup MLP on flagged slots (reuses hot W2h/W3h)
    mfma_gemm_kernel<64, 128, 1, false><<<dim3(CAPF / 64, 4), 256, 0, stream>>>(
        fdh, fdl, nullptr, W2h, W2l, g2, b2, m2, v2, nullptr, hdh, hdl, nullptr, 512);
    mfma_gemm_kernel<64, 512, 3, false><<<dim3(CAPF / 64, 1), 256, 0, stream>>>(
        hdh, hdl, nullptr, W3h, W3l, g3, b3, m3, v3, nullptr, nullptr, nullptr, ydense, 128);
    // F2: blend midpoint into y_out
    fixup_blend_kernel<<<CAPF, 128, 0, stream>>>(fmap, ydense, x, y_out);
}